// Round 20
// baseline (509.322 us; speedup 1.0000x reference)
//
#include <hip/hip_runtime.h>
#include <hip/hip_bf16.h>
#include <stdint.h>

// Problem constants
#define KVOL   27
#define MPAIRS 150000
#define NROWS  200000            // N_IN == N_OUT
#define CDIM   64
#define TOTALC (KVOL*MPAIRS)     // 4,050,000

// Pass / bucket geometry
#define NPASS  3
#define KPP    9                 // k-offsets per pass
#define PASSC  (KPP*MPAIRS)      // 1,350,000 (21 bits)
#define BROWS  128
#define NBKT   1563              // ceil(200000/128)
#define NPB    (NPASS*NBKT)      // 4689 (pass,bucket) bins
#define SUBW   8                 // sub-chunks per k for hist/scatter (divides 150000)
#define NWGH   (KVOL*SUBW)       // 216 WGs
#define CHUNKH (MPAIRS/SUBW)     // 18,750 exact
#define CELLS  (NPB*NWGH)        // 1,012,824 scan cells (sb=990 < 1024)
#define ECAP   1280              // per-(pass,bucket) entry capacity (mean 864, sd 29)

typedef __attribute__((ext_vector_type(8))) short bf16x8;
typedef __attribute__((ext_vector_type(4))) float f32x4;

__device__ __forceinline__ unsigned short f2bfu(float f) {
  union { float f; uint32_t u; } v; v.f = f;
  uint32_t u = v.u;
  u += 0x7FFF + ((u >> 16) & 1);
  return (unsigned short)(u >> 16);
}
__device__ __forceinline__ short f2bf(float f) { return (short)f2bfu(f); }
__device__ __forceinline__ float bf2f(uint32_t u16) {
  union { uint32_t u; float f; } v; v.u = u16 << 16; return v.f;
}

// ---- prologue: fused feats + weights convert (one launch) ----
__global__ void cvt_all(const float* __restrict__ in, short* __restrict__ out,
                        const float* __restrict__ w, short* __restrict__ wt, int n8) {
  if (blockIdx.x < KVOL) {                     // weight transpose blocks
    int k = blockIdx.x;
    const float* wk = w + (size_t)k * CDIM * CDIM;
    short* wtk = wt + (size_t)k * CDIM * CDIM;
    for (int t = threadIdx.x; t < CDIM * CDIM; t += blockDim.x) {
      int j = t >> 6, i = t & 63;
      wtk[j * CDIM + i] = f2bf(wk[i * CDIM + j]);
    }
    return;
  }
  int i = (blockIdx.x - KVOL) * blockDim.x + threadIdx.x;
  int stride = (gridDim.x - KVOL) * blockDim.x;
  for (; i < n8; i += stride) {
    const float* p = in + (size_t)i * 8;
    f32x4 f0 = *(const f32x4*)(p);
    f32x4 f1 = *(const f32x4*)(p + 4);
    bf16x8 o;
    o[0] = f2bf(f0[0]); o[1] = f2bf(f0[1]); o[2] = f2bf(f0[2]); o[3] = f2bf(f0[3]);
    o[4] = f2bf(f1[0]); o[5] = f2bf(f1[1]); o[6] = f2bf(f1[2]); o[7] = f2bf(f1[3]);
    *(bf16x8*)(out + (size_t)i * 8) = o;
  }
}

// ---- histogram: WG = (k, sub-chunk); LDS-private 1563 bucket bins ----
__global__ __launch_bounds__(256)
void k_hist(const int* __restrict__ om, unsigned int* __restrict__ hist_g) {
  __shared__ unsigned int h[NBKT];
  const int wg = blockIdx.x, tid = threadIdx.x;
  const int k = wg / SUBW, sub = wg - k * SUBW;
  const int pass = k / KPP;
  for (int i = tid; i < NBKT; i += 256) h[i] = 0u;
  __syncthreads();
  const int base = k * MPAIRS + sub * CHUNKH;
  for (int i = tid; i < CHUNKH; i += 256)
    atomicAdd(&h[((unsigned)om[base + i]) >> 7], 1u);
  __syncthreads();
  for (int b = tid; b < NBKT; b += 256)
    hist_g[(size_t)(pass * NBKT + b) * NWGH + wg] = h[b];
}

// ---- 3-kernel exclusive scan over CELLS ([bin][wg] cell-major) ----
__global__ void scan_local(const unsigned int* __restrict__ counts,
                           unsigned int* __restrict__ offsets,
                           unsigned int* __restrict__ bsum, int n) {
  __shared__ unsigned int sh[1024];
  int t = threadIdx.x;
  int idx = blockIdx.x * 1024 + t;
  unsigned int v = (idx < n) ? counts[idx] : 0u;
  sh[t] = v; __syncthreads();
  for (int o = 1; o < 1024; o <<= 1) {
    unsigned int u = (t >= o) ? sh[t - o] : 0u;
    __syncthreads();
    sh[t] += u;
    __syncthreads();
  }
  if (idx < n) offsets[idx] = sh[t] - v;
  if (t == 1023) bsum[blockIdx.x] = sh[1023];
}

__global__ void scan_bsum(unsigned int* __restrict__ bsum, int nb) {
  __shared__ unsigned int sh[1024];
  int t = threadIdx.x;
  unsigned int v = (t < nb) ? bsum[t] : 0u;
  sh[t] = v; __syncthreads();
  for (int o = 1; o < 1024; o <<= 1) {
    unsigned int u = (t >= o) ? sh[t - o] : 0u;
    __syncthreads();
    sh[t] += u;
    __syncthreads();
  }
  if (t < nb) bsum[t] = sh[t] - v;
}

__global__ void scan_apply(unsigned int* __restrict__ offsets,
                           const unsigned int* __restrict__ bsum,
                           const unsigned int* __restrict__ counts, int n) {
  int idx = blockIdx.x * 1024 + threadIdx.x;
  if (idx < n) {
    unsigned int o = offsets[idx] + bsum[blockIdx.x];
    offsets[idx] = o;
    if (idx == n - 1) offsets[n] = o + counts[idx];
  }
}

// ---- scatter 4B entries (outl<<21 | e_local) into (pass,bucket) slots ----
__global__ __launch_bounds__(256)
void k_scatter(const int* __restrict__ om,
               const unsigned int* __restrict__ offs, unsigned int* __restrict__ sorted_g) {
  __shared__ unsigned int cur[NBKT];
  const int wg = blockIdx.x, tid = threadIdx.x;
  const int k = wg / SUBW, sub = wg - k * SUBW;
  const int pass = k / KPP, kk = k - pass * KPP;
  for (int b = tid; b < NBKT; b += 256)
    cur[b] = offs[(size_t)(pass * NBKT + b) * NWGH + wg];
  __syncthreads();
  const int base = k * MPAIRS + sub * CHUNKH;
  const unsigned int elb = (unsigned)(kk * MPAIRS + sub * CHUNKH);
  for (int i = tid; i < CHUNKH; i += 256) {
    unsigned int o = (unsigned)om[base + i];
    unsigned int pos = atomicAdd(&cur[o >> 7], 1u);
    sorted_g[pos] = ((o & 127u) << 21) | (elb + (unsigned)i);
  }
}

// ---- GEMM (per pass): ORIGINAL k-major order, coalesced contrib writes,
// zero atomics. Swapped MFMA: lane (r,h) owns pair base+r, channels
// t*16+h*4+{0..3}. Plain short4 stores (R18): NT 8B stores amplified
// writes 169->221MB without protecting the gather table (R19). ----
__global__ __launch_bounds__(256, 8)
void k_gemm(const short* __restrict__ a_bf16, const short* __restrict__ wt_bf16,
            const int* __restrict__ in_map, short* __restrict__ contrib, int pass)
{
  const int kk   = blockIdx.y;
  const int k    = pass * KPP + kk;
  const int lane = threadIdx.x & 63;
  const int wave = threadIdx.x >> 6;
  const int r    = lane & 15;
  const int h    = lane >> 4;

  bf16x8 b[4][2];
  const short* wtk = wt_bf16 + (size_t)k * CDIM * CDIM;
#pragma unroll
  for (int t = 0; t < 4; ++t)
#pragma unroll
    for (int c = 0; c < 2; ++c)
      b[t][c] = *(const bf16x8*)(wtk + (t * 16 + r) * CDIM + c * 32 + h * 8);

  const int* imk = in_map + (size_t)k * MPAIRS;
  const int ntiles = MPAIRS / 16;
  const int wstride = gridDim.x * 4;

  for (int tile = blockIdx.x * 4 + wave; tile < ntiles; tile += wstride) {
    const int base = tile * 16;
    const int in_row = imk[base + r];
    const short* arow = a_bf16 + (size_t)in_row * CDIM;
    bf16x8 a0 = *(const bf16x8*)(arow + h * 8);
    bf16x8 a1 = *(const bf16x8*)(arow + 32 + h * 8);

    f32x4 acc[4];
#pragma unroll
    for (int t = 0; t < 4; ++t) {
      acc[t] = (f32x4){0.f, 0.f, 0.f, 0.f};
      acc[t] = __builtin_amdgcn_mfma_f32_16x16x32_bf16(b[t][0], a0, acc[t], 0, 0, 0);
      acc[t] = __builtin_amdgcn_mfma_f32_16x16x32_bf16(b[t][1], a1, acc[t], 0, 0, 0);
    }

    short* crow = contrib + (size_t)(kk * MPAIRS + base + r) * CDIM;
#pragma unroll
    for (int t = 0; t < 4; ++t) {
      short4 s4;
      s4.x = f2bf(acc[t][0]); s4.y = f2bf(acc[t][1]);
      s4.z = f2bf(acc[t][2]); s4.w = f2bf(acc[t][3]);
      *(short4*)(crow + t * 16 + h * 4) = s4;
    }
  }
}

// ---- reduce (per pass): WG(512) per bucket; in-LDS row-sort (parallel scan);
// accumulate: QUARTER-wave per row (16 lanes x 8B = 4 channels), 4 rows in
// flight per wave, 4/2/1 ladder. Contrib loads NONTEMPORAL (read-once;
// R19 isolated this as the reduce win: ~45 -> ~34 us/pass). ----
__global__ __launch_bounds__(512, 4)
void k_reduce(const short* __restrict__ contrib,
              const unsigned int* __restrict__ sorted_g,
              const unsigned int* __restrict__ offs,
              float* __restrict__ out, int pass)
{
  __shared__ unsigned int ents[ECAP];
  __shared__ unsigned int h[BROWS], bs[BROWS], cur[BROWS];

  const int bkt = blockIdx.x, tid = threadIdx.x;
  const int bin = pass * NBKT + bkt;
  const unsigned int s = offs[(size_t)bin * NWGH];
  const unsigned int e = offs[(size_t)(bin + 1) * NWGH];
  int cnt = (int)(e - s); if (cnt > ECAP) cnt = ECAP;   // astronomically unlikely clamp

  if (tid < BROWS) h[tid] = 0u;
  __syncthreads();
  for (int i = tid; i < cnt; i += 512)
    atomicAdd(&h[sorted_g[s + i] >> 21], 1u);
  __syncthreads();
  // parallel exclusive scan of h -> bs (Kogge-Stone inclusive, then shift)
  if (tid < BROWS) bs[tid] = h[tid];
  __syncthreads();
#pragma unroll
  for (int o = 1; o < BROWS; o <<= 1) {
    unsigned int v = 0;
    if (tid < BROWS && tid >= o) v = bs[tid - o];
    __syncthreads();
    if (tid < BROWS) bs[tid] += v;
    __syncthreads();
  }
  if (tid < BROWS) {
    unsigned int ex = bs[tid] - h[tid];   // exclusive
    bs[tid] = ex;
    cur[tid] = ex;
  }
  __syncthreads();
  for (int i = tid; i < cnt; i += 512) {
    unsigned int en = sorted_g[s + i];
    unsigned int pos = atomicAdd(&cur[en >> 21], 1u);
    ents[pos] = en;
  }
  __syncthreads();

  const int lane = tid & 63, wv = tid >> 6;            // 8 waves
  const int q    = lane >> 4;                          // row quarter 0..3
  const int cl4  = lane & 15;                          // channel quad (4 ch = 8B)
  const unsigned long long* cb = (const unsigned long long*)contrib;  // row = 16 x 8B

#pragma unroll 1
  for (int rp = 0; rp < 4; ++rp) {                     // 4 iters x 4 rows = 16 rows/wave
    const int row  = wv * 16 + rp * 4 + q;
    const int grow = bkt * BROWS + row;
    const bool active = (grow < NROWS) && !(h[row] == 0u && pass);
    if (active) {
      float a0 = 0.f, a1 = 0.f, a2 = 0.f, a3 = 0.f;
      float b0 = 0.f, b1 = 0.f, b2 = 0.f, b3 = 0.f;
      int j = (int)bs[row];
      const int je = j + (int)h[row];
      for (; j + 3 < je; j += 4) {                     // 4-deep
        unsigned long long w0 = __builtin_nontemporal_load(&cb[(size_t)(ents[j]     & 0x1FFFFFu) * 16 + cl4]);
        unsigned long long w1 = __builtin_nontemporal_load(&cb[(size_t)(ents[j + 1] & 0x1FFFFFu) * 16 + cl4]);
        unsigned long long w2 = __builtin_nontemporal_load(&cb[(size_t)(ents[j + 2] & 0x1FFFFFu) * 16 + cl4]);
        unsigned long long w3 = __builtin_nontemporal_load(&cb[(size_t)(ents[j + 3] & 0x1FFFFFu) * 16 + cl4]);
        a0 += bf2f((uint32_t)w0 & 0xFFFFu); a1 += bf2f(((uint32_t)w0) >> 16);
        a2 += bf2f((uint32_t)(w0 >> 32) & 0xFFFFu); a3 += bf2f((uint32_t)(w0 >> 48));
        b0 += bf2f((uint32_t)w1 & 0xFFFFu); b1 += bf2f(((uint32_t)w1) >> 16);
        b2 += bf2f((uint32_t)(w1 >> 32) & 0xFFFFu); b3 += bf2f((uint32_t)(w1 >> 48));
        a0 += bf2f((uint32_t)w2 & 0xFFFFu); a1 += bf2f(((uint32_t)w2) >> 16);
        a2 += bf2f((uint32_t)(w2 >> 32) & 0xFFFFu); a3 += bf2f((uint32_t)(w2 >> 48));
        b0 += bf2f((uint32_t)w3 & 0xFFFFu); b1 += bf2f(((uint32_t)w3) >> 16);
        b2 += bf2f((uint32_t)(w3 >> 32) & 0xFFFFu); b3 += bf2f((uint32_t)(w3 >> 48));
      }
      if (j + 1 < je) {                                // 2-deep tail
        unsigned long long w0 = __builtin_nontemporal_load(&cb[(size_t)(ents[j]     & 0x1FFFFFu) * 16 + cl4]);
        unsigned long long w1 = __builtin_nontemporal_load(&cb[(size_t)(ents[j + 1] & 0x1FFFFFu) * 16 + cl4]);
        a0 += bf2f((uint32_t)w0 & 0xFFFFu); a1 += bf2f(((uint32_t)w0) >> 16);
        a2 += bf2f((uint32_t)(w0 >> 32) & 0xFFFFu); a3 += bf2f((uint32_t)(w0 >> 48));
        b0 += bf2f((uint32_t)w1 & 0xFFFFu); b1 += bf2f(((uint32_t)w1) >> 16);
        b2 += bf2f((uint32_t)(w1 >> 32) & 0xFFFFu); b3 += bf2f((uint32_t)(w1 >> 48));
        j += 2;
      }
      if (j < je) {                                    // 1 tail
        unsigned long long w0 = __builtin_nontemporal_load(&cb[(size_t)(ents[j] & 0x1FFFFFu) * 16 + cl4]);
        a0 += bf2f((uint32_t)w0 & 0xFFFFu); a1 += bf2f(((uint32_t)w0) >> 16);
        a2 += bf2f((uint32_t)(w0 >> 32) & 0xFFFFu); a3 += bf2f((uint32_t)(w0 >> 48));
      }
      a0 += b0; a1 += b1; a2 += b2; a3 += b3;
      float* op = out + (size_t)grow * CDIM + cl4 * 4;
      if (pass) {
        float4 prev = *(const float4*)op;
        a0 += prev.x; a1 += prev.y; a2 += prev.z; a3 += prev.w;
      }
      float4 o4; o4.x = a0; o4.y = a1; o4.z = a2; o4.w = a3;
      *(float4*)op = o4;
    }
  }
}

extern "C" void kernel_launch(void* const* d_in, const int* in_sizes, int n_in,
                              void* d_out, int out_size, void* d_ws, size_t ws_size,
                              hipStream_t stream) {
  const float* in_feats = (const float*)d_in[0];
  const float* kernel   = (const float*)d_in[1];
  const int*   in_map   = (const int*)d_in[2];
  const int*   out_map  = (const int*)d_in[3];
  float* out = (float*)d_out;

  uint8_t* ws = (uint8_t*)d_ws;
  size_t off = 0;
  auto alloc = [&](size_t bytes) -> void* {
    void* p = ws + off;
    off += (bytes + 255) & ~(size_t)255;
    return p;
  };
  short* in_bf16         = (short*)alloc((size_t)NROWS * CDIM * 2);        // 25.6 MB
  short* wt_bf16         = (short*)alloc((size_t)KVOL * CDIM * CDIM * 2);  // 221 KB
  unsigned int* hist_g   = (unsigned int*)alloc((size_t)CELLS * 4);        // 4.05 MB
  unsigned int* offs     = (unsigned int*)alloc((size_t)(CELLS + 1) * 4);  // 4.05 MB
  unsigned int* bsum     = (unsigned int*)alloc(4096);
  unsigned int* sorted_g = (unsigned int*)alloc((size_t)TOTALC * 4);       // 16.2 MB
  short* contrib         = (short*)alloc((size_t)PASSC * CDIM * 2);        // 172.8 MB

  hipMemsetAsync(hist_g, 0, (size_t)CELLS * 4, stream);

  cvt_all<<<2048 + KVOL, 256, 0, stream>>>(in_feats, in_bf16, kernel, wt_bf16,
                                           NROWS * CDIM / 8);

  k_hist<<<NWGH, 256, 0, stream>>>(out_map, hist_g);

  const int sb = (CELLS + 1023) / 1024;   // 990 (< 1024: scan_bsum single-block OK)
  scan_local<<<sb, 1024, 0, stream>>>(hist_g, offs, bsum, CELLS);
  scan_bsum<<<1, 1024, 0, stream>>>(bsum, sb);
  scan_apply<<<sb, 1024, 0, stream>>>(offs, bsum, hist_g, CELLS);

  k_scatter<<<NWGH, 256, 0, stream>>>(out_map, offs, sorted_g);

  for (int p = 0; p < NPASS; ++p) {
    dim3 g(227, KPP);   // 2043 blocks ~= 8/CU capacity
    k_gemm<<<g, 256, 0, stream>>>(in_bf16, wt_bf16, in_map, contrib, p);
    k_reduce<<<NBKT, 512, 0, stream>>>(contrib, sorted_g, offs, out, p);
  }
}

// Round 22
// 441.491 us; speedup vs baseline: 1.1536x; 1.1536x over previous
//
#include <hip/hip_runtime.h>
#include <hip/hip_bf16.h>
#include <stdint.h>

// Problem constants
#define KVOL   27
#define MPAIRS 150000
#define NROWS  200000            // N_IN == N_OUT
#define CDIM   64
#define TOTALC (KVOL*MPAIRS)     // 4,050,000

// Pass / bucket geometry
#define NPASS  3
#define KPP    9                 // k-offsets per pass
#define PASSC  (KPP*MPAIRS)      // 1,350,000 (21 bits)
#define BROWS  128
#define NBKT   1563              // ceil(200000/128)
#define NPB    (NPASS*NBKT)      // 4689 (pass,bucket) bins
#define SUBW   8                 // sub-chunks per k for hist/scatter (divides 150000)
#define NWGH   (KVOL*SUBW)       // 216 WGs
#define CHUNKH (MPAIRS/SUBW)     // 18,750 exact
#define CELLS  (NPB*NWGH)        // 1,012,824 scan cells (sb=990 < 1024)
#define ECAP   1280              // per-(pass,bucket) entry capacity (mean 864, sd 29)

typedef __attribute__((ext_vector_type(8))) short bf16x8;
typedef __attribute__((ext_vector_type(4))) float f32x4;
typedef __attribute__((ext_vector_type(2))) unsigned long long u64x2;

__device__ __forceinline__ unsigned short f2bfu(float f) {
  union { float f; uint32_t u; } v; v.f = f;
  uint32_t u = v.u;
  u += 0x7FFF + ((u >> 16) & 1);
  return (unsigned short)(u >> 16);
}
__device__ __forceinline__ short f2bf(float f) { return (short)f2bfu(f); }
__device__ __forceinline__ float bf2f(uint32_t u16) {
  union { uint32_t u; float f; } v; v.u = u16 << 16; return v.f;
}

// ---- prologue: fused feats + weights convert (one launch) ----
__global__ void cvt_all(const float* __restrict__ in, short* __restrict__ out,
                        const float* __restrict__ w, short* __restrict__ wt, int n8) {
  if (blockIdx.x < KVOL) {                     // weight transpose blocks
    int k = blockIdx.x;
    const float* wk = w + (size_t)k * CDIM * CDIM;
    short* wtk = wt + (size_t)k * CDIM * CDIM;
    for (int t = threadIdx.x; t < CDIM * CDIM; t += blockDim.x) {
      int j = t >> 6, i = t & 63;
      wtk[j * CDIM + i] = f2bf(wk[i * CDIM + j]);
    }
    return;
  }
  int i = (blockIdx.x - KVOL) * blockDim.x + threadIdx.x;
  int stride = (gridDim.x - KVOL) * blockDim.x;
  for (; i < n8; i += stride) {
    const float* p = in + (size_t)i * 8;
    f32x4 f0 = *(const f32x4*)(p);
    f32x4 f1 = *(const f32x4*)(p + 4);
    bf16x8 o;
    o[0] = f2bf(f0[0]); o[1] = f2bf(f0[1]); o[2] = f2bf(f0[2]); o[3] = f2bf(f0[3]);
    o[4] = f2bf(f1[0]); o[5] = f2bf(f1[1]); o[6] = f2bf(f1[2]); o[7] = f2bf(f1[3]);
    *(bf16x8*)(out + (size_t)i * 8) = o;
  }
}

// ---- histogram: WG = (k, sub-chunk); LDS-private 1563 bucket bins ----
__global__ __launch_bounds__(256)
void k_hist(const int* __restrict__ om, unsigned int* __restrict__ hist_g) {
  __shared__ unsigned int h[NBKT];
  const int wg = blockIdx.x, tid = threadIdx.x;
  const int k = wg / SUBW, sub = wg - k * SUBW;
  const int pass = k / KPP;
  for (int i = tid; i < NBKT; i += 256) h[i] = 0u;
  __syncthreads();
  const int base = k * MPAIRS + sub * CHUNKH;
  for (int i = tid; i < CHUNKH; i += 256)
    atomicAdd(&h[((unsigned)om[base + i]) >> 7], 1u);
  __syncthreads();
  for (int b = tid; b < NBKT; b += 256)
    hist_g[(size_t)(pass * NBKT + b) * NWGH + wg] = h[b];
}

// ---- 3-kernel exclusive scan over CELLS ([bin][wg] cell-major) ----
__global__ void scan_local(const unsigned int* __restrict__ counts,
                           unsigned int* __restrict__ offsets,
                           unsigned int* __restrict__ bsum, int n) {
  __shared__ unsigned int sh[1024];
  int t = threadIdx.x;
  int idx = blockIdx.x * 1024 + t;
  unsigned int v = (idx < n) ? counts[idx] : 0u;
  sh[t] = v; __syncthreads();
  for (int o = 1; o < 1024; o <<= 1) {
    unsigned int u = (t >= o) ? sh[t - o] : 0u;
    __syncthreads();
    sh[t] += u;
    __syncthreads();
  }
  if (idx < n) offsets[idx] = sh[t] - v;
  if (t == 1023) bsum[blockIdx.x] = sh[1023];
}

__global__ void scan_bsum(unsigned int* __restrict__ bsum, int nb) {
  __shared__ unsigned int sh[1024];
  int t = threadIdx.x;
  unsigned int v = (t < nb) ? bsum[t] : 0u;
  sh[t] = v; __syncthreads();
  for (int o = 1; o < 1024; o <<= 1) {
    unsigned int u = (t >= o) ? sh[t - o] : 0u;
    __syncthreads();
    sh[t] += u;
    __syncthreads();
  }
  if (t < nb) bsum[t] = sh[t] - v;
}

__global__ void scan_apply(unsigned int* __restrict__ offsets,
                           const unsigned int* __restrict__ bsum,
                           const unsigned int* __restrict__ counts, int n) {
  int idx = blockIdx.x * 1024 + threadIdx.x;
  if (idx < n) {
    unsigned int o = offsets[idx] + bsum[blockIdx.x];
    offsets[idx] = o;
    if (idx == n - 1) offsets[n] = o + counts[idx];
  }
}

// ---- scatter 4B entries (outl<<21 | e_local) into (pass,bucket) slots ----
__global__ __launch_bounds__(256)
void k_scatter(const int* __restrict__ om,
               const unsigned int* __restrict__ offs, unsigned int* __restrict__ sorted_g) {
  __shared__ unsigned int cur[NBKT];
  const int wg = blockIdx.x, tid = threadIdx.x;
  const int k = wg / SUBW, sub = wg - k * SUBW;
  const int pass = k / KPP, kk = k - pass * KPP;
  for (int b = tid; b < NBKT; b += 256)
    cur[b] = offs[(size_t)(pass * NBKT + b) * NWGH + wg];
  __syncthreads();
  const int base = k * MPAIRS + sub * CHUNKH;
  const unsigned int elb = (unsigned)(kk * MPAIRS + sub * CHUNKH);
  for (int i = tid; i < CHUNKH; i += 256) {
    unsigned int o = (unsigned)om[base + i];
    unsigned int pos = atomicAdd(&cur[o >> 7], 1u);
    sorted_g[pos] = ((o & 127u) << 21) | (elb + (unsigned)i);
  }
}

// ---- GEMM (per pass): ORIGINAL k-major order, zero atomics. Swapped MFMA:
// lane (r,h) owns pair base+r, channels t*16+h*4+{0..3}. NT stores with
// FULL-LINE coverage: one shfl_xor(lane^16) stage swaps h-bit0 with t-bit0
// so each lane holds 2x16B contiguous channel chunks; each store instr
// covers complete 64B lines (fixes R19's 169->221MB NT amplification). ----
__global__ __launch_bounds__(256, 8)
void k_gemm(const short* __restrict__ a_bf16, const short* __restrict__ wt_bf16,
            const int* __restrict__ in_map, short* __restrict__ contrib, int pass)
{
  const int kk   = blockIdx.y;
  const int k    = pass * KPP + kk;
  const int lane = threadIdx.x & 63;
  const int wave = threadIdx.x >> 6;
  const int r    = lane & 15;
  const int h    = lane >> 4;

  bf16x8 b[4][2];
  const short* wtk = wt_bf16 + (size_t)k * CDIM * CDIM;
#pragma unroll
  for (int t = 0; t < 4; ++t)
#pragma unroll
    for (int c = 0; c < 2; ++c)
      b[t][c] = *(const bf16x8*)(wtk + (t * 16 + r) * CDIM + c * 32 + h * 8);

  const int* imk = in_map + (size_t)k * MPAIRS;
  const int ntiles = MPAIRS / 16;
  const int wstride = gridDim.x * 4;

  const int p0 = h & 1, p1 = h >> 1;

  for (int tile = blockIdx.x * 4 + wave; tile < ntiles; tile += wstride) {
    const int base = tile * 16;
    const int in_row = imk[base + r];
    const short* arow = a_bf16 + (size_t)in_row * CDIM;
    bf16x8 a0 = *(const bf16x8*)(arow + h * 8);
    bf16x8 a1 = *(const bf16x8*)(arow + 32 + h * 8);

    f32x4 acc[4];
#pragma unroll
    for (int t = 0; t < 4; ++t) {
      acc[t] = (f32x4){0.f, 0.f, 0.f, 0.f};
      acc[t] = __builtin_amdgcn_mfma_f32_16x16x32_bf16(b[t][0], a0, acc[t], 0, 0, 0);
      acc[t] = __builtin_amdgcn_mfma_f32_16x16x32_bf16(b[t][1], a1, acc[t], 0, 0, 0);
    }

    // pack each acc quad -> 8B bf16
    unsigned long long pk0, pk1, pk2, pk3;
    {
      unsigned long long p_[4];
#pragma unroll
      for (int t = 0; t < 4; ++t)
        p_[t] = (unsigned long long)f2bfu(acc[t][0])
              | ((unsigned long long)f2bfu(acc[t][1]) << 16)
              | ((unsigned long long)f2bfu(acc[t][2]) << 32)
              | ((unsigned long long)f2bfu(acc[t][3]) << 48);
      pk0 = p_[0]; pk1 = p_[1]; pk2 = p_[2]; pk3 = p_[3];
    }
    // exchange across lane^16: swap h-bit0 with t-bit0
    {
      unsigned long long s1 = p0 ? pk0 : pk1;
      s1 = __shfl_xor(s1, 16);
      if (p0) pk0 = s1; else pk1 = s1;
      unsigned long long s3 = p0 ? pk2 : pk3;
      s3 = __shfl_xor(s3, 16);
      if (p0) pk2 = s3; else pk3 = s3;
    }
    // lane (p1,p0) now holds channels {16p0+8p1 + 0..7} (pk0|pk1) and
    // {32+16p0+8p1 + 0..7} (pk2|pk3): 2 x 16B contiguous NT stores.
    short* crow = contrib + (size_t)(kk * MPAIRS + base + r) * CDIM;
    u64x2 A; A[0] = pk0; A[1] = pk1;
    u64x2 B; B[0] = pk2; B[1] = pk3;
    __builtin_nontemporal_store(A, (u64x2*)(crow + p0 * 16 + p1 * 8));
    __builtin_nontemporal_store(B, (u64x2*)(crow + 32 + p0 * 16 + p1 * 8));
  }
}

// ---- reduce (per pass): WG(512) per bucket; in-LDS row-sort (parallel scan);
// accumulate: QUARTER-wave per row (16 lanes x 8B = 4 channels), 4 rows in
// flight per wave, 4/2/1 ladder. Contrib loads NONTEMPORAL (read-once). ----
__global__ __launch_bounds__(512, 4)
void k_reduce(const short* __restrict__ contrib,
              const unsigned int* __restrict__ sorted_g,
              const unsigned int* __restrict__ offs,
              float* __restrict__ out, int pass)
{
  __shared__ unsigned int ents[ECAP];
  __shared__ unsigned int h[BROWS], bs[BROWS], cur[BROWS];

  const int bkt = blockIdx.x, tid = threadIdx.x;
  const int bin = pass * NBKT + bkt;
  const unsigned int s = offs[(size_t)bin * NWGH];
  const unsigned int e = offs[(size_t)(bin + 1) * NWGH];
  int cnt = (int)(e - s); if (cnt > ECAP) cnt = ECAP;   // astronomically unlikely clamp

  if (tid < BROWS) h[tid] = 0u;
  __syncthreads();
  for (int i = tid; i < cnt; i += 512)
    atomicAdd(&h[sorted_g[s + i] >> 21], 1u);
  __syncthreads();
  // parallel exclusive scan of h -> bs (Kogge-Stone inclusive, then shift)
  if (tid < BROWS) bs[tid] = h[tid];
  __syncthreads();
#pragma unroll
  for (int o = 1; o < BROWS; o <<= 1) {
    unsigned int v = 0;
    if (tid < BROWS && tid >= o) v = bs[tid - o];
    __syncthreads();
    if (tid < BROWS) bs[tid] += v;
    __syncthreads();
  }
  if (tid < BROWS) {
    unsigned int ex = bs[tid] - h[tid];   // exclusive
    bs[tid] = ex;
    cur[tid] = ex;
  }
  __syncthreads();
  for (int i = tid; i < cnt; i += 512) {
    unsigned int en = sorted_g[s + i];
    unsigned int pos = atomicAdd(&cur[en >> 21], 1u);
    ents[pos] = en;
  }
  __syncthreads();

  const int lane = tid & 63, wv = tid >> 6;            // 8 waves
  const int q    = lane >> 4;                          // row quarter 0..3
  const int cl4  = lane & 15;                          // channel quad (4 ch = 8B)
  const unsigned long long* cb = (const unsigned long long*)contrib;  // row = 16 x 8B

#pragma unroll 1
  for (int rp = 0; rp < 4; ++rp) {                     // 4 iters x 4 rows = 16 rows/wave
    const int row  = wv * 16 + rp * 4 + q;
    const int grow = bkt * BROWS + row;
    const bool active = (grow < NROWS) && !(h[row] == 0u && pass);
    if (active) {
      float a0 = 0.f, a1 = 0.f, a2 = 0.f, a3 = 0.f;
      float b0 = 0.f, b1 = 0.f, b2 = 0.f, b3 = 0.f;
      int j = (int)bs[row];
      const int je = j + (int)h[row];
      for (; j + 3 < je; j += 4) {                     // 4-deep
        unsigned long long w0 = __builtin_nontemporal_load(&cb[(size_t)(ents[j]     & 0x1FFFFFu) * 16 + cl4]);
        unsigned long long w1 = __builtin_nontemporal_load(&cb[(size_t)(ents[j + 1] & 0x1FFFFFu) * 16 + cl4]);
        unsigned long long w2 = __builtin_nontemporal_load(&cb[(size_t)(ents[j + 2] & 0x1FFFFFu) * 16 + cl4]);
        unsigned long long w3 = __builtin_nontemporal_load(&cb[(size_t)(ents[j + 3] & 0x1FFFFFu) * 16 + cl4]);
        a0 += bf2f((uint32_t)w0 & 0xFFFFu); a1 += bf2f(((uint32_t)w0) >> 16);
        a2 += bf2f((uint32_t)(w0 >> 32) & 0xFFFFu); a3 += bf2f((uint32_t)(w0 >> 48));
        b0 += bf2f((uint32_t)w1 & 0xFFFFu); b1 += bf2f(((uint32_t)w1) >> 16);
        b2 += bf2f((uint32_t)(w1 >> 32) & 0xFFFFu); b3 += bf2f((uint32_t)(w1 >> 48));
        a0 += bf2f((uint32_t)w2 & 0xFFFFu); a1 += bf2f(((uint32_t)w2) >> 16);
        a2 += bf2f((uint32_t)(w2 >> 32) & 0xFFFFu); a3 += bf2f((uint32_t)(w2 >> 48));
        b0 += bf2f((uint32_t)w3 & 0xFFFFu); b1 += bf2f(((uint32_t)w3) >> 16);
        b2 += bf2f((uint32_t)(w3 >> 32) & 0xFFFFu); b3 += bf2f((uint32_t)(w3 >> 48));
      }
      if (j + 1 < je) {                                // 2-deep tail
        unsigned long long w0 = __builtin_nontemporal_load(&cb[(size_t)(ents[j]     & 0x1FFFFFu) * 16 + cl4]);
        unsigned long long w1 = __builtin_nontemporal_load(&cb[(size_t)(ents[j + 1] & 0x1FFFFFu) * 16 + cl4]);
        a0 += bf2f((uint32_t)w0 & 0xFFFFu); a1 += bf2f(((uint32_t)w0) >> 16);
        a2 += bf2f((uint32_t)(w0 >> 32) & 0xFFFFu); a3 += bf2f((uint32_t)(w0 >> 48));
        b0 += bf2f((uint32_t)w1 & 0xFFFFu); b1 += bf2f(((uint32_t)w1) >> 16);
        b2 += bf2f((uint32_t)(w1 >> 32) & 0xFFFFu); b3 += bf2f((uint32_t)(w1 >> 48));
        j += 2;
      }
      if (j < je) {                                    // 1 tail
        unsigned long long w0 = __builtin_nontemporal_load(&cb[(size_t)(ents[j] & 0x1FFFFFu) * 16 + cl4]);
        a0 += bf2f((uint32_t)w0 & 0xFFFFu); a1 += bf2f(((uint32_t)w0) >> 16);
        a2 += bf2f((uint32_t)(w0 >> 32) & 0xFFFFu); a3 += bf2f((uint32_t)(w0 >> 48));
      }
      a0 += b0; a1 += b1; a2 += b2; a3 += b3;
      float* op = out + (size_t)grow * CDIM + cl4 * 4;
      if (pass) {
        float4 prev = *(const float4*)op;
        a0 += prev.x; a1 += prev.y; a2 += prev.z; a3 += prev.w;
      }
      float4 o4; o4.x = a0; o4.y = a1; o4.z = a2; o4.w = a3;
      *(float4*)op = o4;
    }
  }
}

extern "C" void kernel_launch(void* const* d_in, const int* in_sizes, int n_in,
                              void* d_out, int out_size, void* d_ws, size_t ws_size,
                              hipStream_t stream) {
  const float* in_feats = (const float*)d_in[0];
  const float* kernel   = (const float*)d_in[1];
  const int*   in_map   = (const int*)d_in[2];
  const int*   out_map  = (const int*)d_in[3];
  float* out = (float*)d_out;

  uint8_t* ws = (uint8_t*)d_ws;
  size_t off = 0;
  auto alloc = [&](size_t bytes) -> void* {
    void* p = ws + off;
    off += (bytes + 255) & ~(size_t)255;
    return p;
  };
  short* in_bf16         = (short*)alloc((size_t)NROWS * CDIM * 2);        // 25.6 MB
  short* wt_bf16         = (short*)alloc((size_t)KVOL * CDIM * CDIM * 2);  // 221 KB
  unsigned int* hist_g   = (unsigned int*)alloc((size_t)CELLS * 4);        // 4.05 MB
  unsigned int* offs     = (unsigned int*)alloc((size_t)(CELLS + 1) * 4);  // 4.05 MB
  unsigned int* bsum     = (unsigned int*)alloc(4096);
  unsigned int* sorted_g = (unsigned int*)alloc((size_t)TOTALC * 4);       // 16.2 MB
  short* contrib         = (short*)alloc((size_t)PASSC * CDIM * 2);        // 172.8 MB

  hipMemsetAsync(hist_g, 0, (size_t)CELLS * 4, stream);

  cvt_all<<<2048 + KVOL, 256, 0, stream>>>(in_feats, in_bf16, kernel, wt_bf16,
                                           NROWS * CDIM / 8);

  k_hist<<<NWGH, 256, 0, stream>>>(out_map, hist_g);

  const int sb = (CELLS + 1023) / 1024;   // 990 (< 1024: scan_bsum single-block OK)
  scan_local<<<sb, 1024, 0, stream>>>(hist_g, offs, bsum, CELLS);
  scan_bsum<<<1, 1024, 0, stream>>>(bsum, sb);
  scan_apply<<<sb, 1024, 0, stream>>>(offs, bsum, hist_g, CELLS);

  k_scatter<<<NWGH, 256, 0, stream>>>(out_map, offs, sorted_g);

  for (int p = 0; p < NPASS; ++p) {
    dim3 g(227, KPP);   // 2043 blocks ~= 8/CU capacity
    k_gemm<<<g, 256, 0, stream>>>(in_bf16, wt_bf16, in_map, contrib, p);
    k_reduce<<<NBKT, 512, 0, stream>>>(contrib, sorted_g, offs, out, p);
  }
}